// Round 4
// baseline (195.486 us; speedup 1.0000x reference)
//
#include <hip/hip_runtime.h>
#include <hip/hip_bf16.h>

// Problem: x(4,256,64,64), offset(4,18,64,64), mask(4,9,64,64),
// weight(256,256,3,3) -> out(4,256,64,64). stride=1, pad=1, K=3.
// Pipeline: prep (BCHW->BHWC fp32 | weight->bf16 [O][kk*256+c] | zero out)
//   -> sample (bilinear+modulate -> A[16384][2304] bf16)
//   -> GEMM (M=16384,N=256,K=2304 bf16 MFMA, K-split=2, atomic f32 epilogue).
// R4: LDS tiles stored MFMA-fragment-ordered (chunk = frag_group*64 + lane) so
// every ds_read_b128 is base+lane*16 (identity stream, zero bank conflicts).
#define BN 4
#define CN 256
#define HN 64
#define WN 64
#define ON 256
#define KKN 9
#define HWN 4096
#define KDIM 2304   // 9*256
#define MN 16384    // B*H*W
#define KHALF 1152  // K-split = 2

using frag_ab = __attribute__((ext_vector_type(8))) short;  // 8 bf16
using frag_cd = __attribute__((ext_vector_type(4))) float;  // 4 fp32

static __device__ inline short f2bf(float f) {
    union { float f; unsigned u; } v; v.f = f;
    unsigned r = v.u + 0x7fffu + ((v.u >> 16) & 1u);
    return (short)(r >> 16);
}

static __device__ inline void async_copy16(const void* g, void* l) {
    __builtin_amdgcn_global_load_lds(
        (const __attribute__((address_space(1))) unsigned int*)g,
        (__attribute__((address_space(3))) unsigned int*)l,
        16, 0, 0);
}

// ---------- kernel 1: prep = transpose_x | repack_w | zero_out ----------
__global__ __launch_bounds__(256) void prep_kernel(const float* __restrict__ x,
                                                   const float* __restrict__ wsrc,
                                                   float* __restrict__ xb,
                                                   short* __restrict__ wt,
                                                   float* __restrict__ outz) {
    int bidx = blockIdx.x;
    int tid  = threadIdx.x;
    if (bidx < 1024) {
        __shared__ float tile[64][65];
        int b   = bidx >> 8;
        int rem = bidx & 255;
        int c0  = (rem >> 6) * 64;
        int p0  = (rem & 63) * 64;
        int tp = tid & 63, tc = tid >> 6;
        for (int i = 0; i < 16; ++i) {
            int c = tc + i * 4;
            tile[c][tp] = x[(b * CN + c0 + c) * HWN + p0 + tp];
        }
        __syncthreads();
        int tcc = tid & 63, tpp = tid >> 6;
        for (int i = 0; i < 16; ++i) {
            int p = tpp + i * 4;
            xb[(b * HWN + p0 + p) * CN + c0 + tcc] = tile[tcc][p];
        }
    } else if (bidx < 3328) {
        int t = (bidx - 1024) * 256 + tid;    // < 589824
        int c = t & 255;
        int rest = t >> 8;                    // o*9 + kk
        int kk = rest % 9;
        int o  = rest / 9;
        float v = wsrc[(o * CN + c) * 9 + kk];
        wt[o * KDIM + kk * CN + c] = f2bf(v);
    } else {
        int t = (bidx - 3328) * 256 + tid;    // < 262144, 16 floats each
        float4 z = {0.f, 0.f, 0.f, 0.f};
        float4* p = (float4*)outz + (size_t)t * 4;
        p[0] = z; p[1] = z; p[2] = z; p[3] = z;
    }
}

// ---------- kernel 2: bilinear sample + modulate -> A[m][kk*256+c] bf16 ----
// grid = MN/4 blocks x 256 threads; wave handles one m, lane = c-quad.
__global__ __launch_bounds__(256) void sample_kernel(const float* __restrict__ xb,
                                                     const float* __restrict__ offs,
                                                     const float* __restrict__ maskp,
                                                     short* __restrict__ A) {
    int t  = threadIdx.x;
    int m  = blockIdx.x * 4 + (t >> 6);      // wave-uniform
    int b  = m >> 12;
    int h  = (m >> 6) & 63;
    int w  = m & 63;
    int c0 = (t & 63) * 4;
    #pragma unroll
    for (int kk = 0; kk < KKN; ++kk) {
        int ki = kk / 3, kj = kk - ki * 3;
        int obase = ((b * 18 + kk * 2) * 64 + h) * 64 + w;
        float dy = offs[obase];
        float dx = offs[obase + HWN];
        float mv = maskp[((b * 9 + kk) * 64 + h) * 64 + w];
        float py = (float)(h - 1 + ki) + dy;
        float px = (float)(w - 1 + kj) + dx;
        float y0f = floorf(py), x0f = floorf(px);
        float wy = py - y0f, wx = px - x0f;
        int y0 = (int)y0f, x0 = (int)x0f;
        float4 acc = {0.f, 0.f, 0.f, 0.f};
        #pragma unroll
        for (int cy = 0; cy < 2; ++cy)
            #pragma unroll
            for (int cx = 0; cx < 2; ++cx) {
                int yy = y0 + cy, xx = x0 + cx;
                // wave-uniform branch: all 64 lanes share (m,kk)
                if (yy >= 0 && yy < HN && xx >= 0 && xx < WN) {
                    float wgt = (cy ? wy : 1.f - wy) * (cx ? wx : 1.f - wx) * mv;
                    const float4 vv =
                        *(const float4*)&xb[(((b * HN + yy) * WN + xx) << 8) + c0];
                    acc.x += wgt * vv.x;
                    acc.y += wgt * vv.y;
                    acc.z += wgt * vv.z;
                    acc.w += wgt * vv.w;
                }
            }
        union { __hip_bfloat162 h2[2]; short4 s4; } u;
        u.h2[0] = __float22bfloat162_rn(make_float2(acc.x, acc.y));
        u.h2[1] = __float22bfloat162_rn(make_float2(acc.z, acc.w));
        *(short4*)&A[(size_t)m * KDIM + kk * CN + c0] = u.s4;
    }
}

// ---------- kernel 3: GEMM with K-split, atomic f32 epilogue ----------
// MT=128, NT=64, BK=64. grid = 128 mblk * 4 oblk * 2 ks = 1024 blocks.
// bid: mblk = bid&127 -> the 8 blocks sharing an A-tile land on one XCD.
// LDS chunk order (16B chunks): A chunk CI = ((row>>5)*4+((row>>4)&1)*2+(kc>>2))*64
//   + (kc&3)*16 + (row&15); frag read (wv,i,s) = chunks [(wv*4+i*2+s)*64 + lane].
// B: CI = ((row>>4)*2+(kc>>2))*64 + (kc&3)*16 + (row&15).
#define MT 128
#define NT 64
#define BK 64

__global__ __launch_bounds__(256, 4) void gemm_kernel(const short* __restrict__ A,
                                                      const short* __restrict__ wt,
                                                      float* __restrict__ out) {
    __shared__ union {
        struct { short A[MT * BK]; short B[NT * BK]; } st;  // 16 KB + 8 KB
        float outb[MT][65];                                  // 33.3 KB
    } sm;
    int tid  = threadIdx.x;
    int bid  = blockIdx.x;
    int mblk = bid & 127;
    int g    = bid >> 7;
    int oblk = g >> 1;
    int ks   = g & 1;
    int m0 = mblk * MT, o0 = oblk * NT;
    int kbeg = ks * KHALF;
    int wv = tid >> 6, lane = tid & 63;
    int q = lane >> 4, r = lane & 15;

    frag_cd acc[2][4];
    #pragma unroll
    for (int i = 0; i < 2; ++i)
        #pragma unroll
        for (int j = 0; j < 4; ++j)
            acc[i][j] = (frag_cd){0.f, 0.f, 0.f, 0.f};

    // staging descriptors: wave wv fills chunk groups ga = wv*4+it (A),
    // gb = wv*2+it (B); lane l supplies chunk (g*64 + l).
    const short* pA[4]; short* lA[4];
    #pragma unroll
    for (int it = 0; it < 4; ++it) {
        int ga  = wv * 4 + it;
        int row = (ga >> 2) * 32 + ((ga >> 1) & 1) * 16 + r;
        int kc  = (ga & 1) * 4 + q;
        pA[it] = A + (size_t)(m0 + row) * KDIM + kbeg + kc * 8;
        lA[it] = sm.st.A + (ga * 64 + lane) * 8;
    }
    const short* pB[2]; short* lB[2];
    #pragma unroll
    for (int it = 0; it < 2; ++it) {
        int gb  = wv * 2 + it;
        int row = (gb >> 1) * 16 + r;
        int kc  = (gb & 1) * 4 + q;
        pB[it] = wt + (size_t)(o0 + row) * KDIM + kbeg + kc * 8;
        lB[it] = sm.st.B + (gb * 64 + lane) * 8;
    }

    for (int k0 = 0; k0 < KHALF; k0 += BK) {
        __syncthreads();
        #pragma unroll
        for (int it = 0; it < 4; ++it) async_copy16(pA[it] + k0, lA[it]);
        #pragma unroll
        for (int it = 0; it < 2; ++it) async_copy16(pB[it] + k0, lB[it]);
        __syncthreads();
        #pragma unroll
        for (int s = 0; s < 2; ++s) {
            frag_ab af[2], bf[4];
            #pragma unroll
            for (int i = 0; i < 2; ++i)
                af[i] = *(const frag_ab*)
                    &sm.st.A[((wv * 4 + i * 2 + s) * 64 + lane) * 8];
            #pragma unroll
            for (int j = 0; j < 4; ++j)
                bf[j] = *(const frag_ab*)
                    &sm.st.B[((j * 2 + s) * 64 + lane) * 8];
            #pragma unroll
            for (int i = 0; i < 2; ++i)
                #pragma unroll
                for (int j = 0; j < 4; ++j)
                    acc[i][j] = __builtin_amdgcn_mfma_f32_16x16x32_bf16(
                        af[i], bf[j], acc[i][j], 0, 0, 0);
        }
    }
    __syncthreads();
    // epilogue: C-frag (row = q*4+reg, col = r) -> LDS -> atomic BOHW adds
    #pragma unroll
    for (int i = 0; i < 2; ++i)
        #pragma unroll
        for (int j = 0; j < 4; ++j) {
            int ml = wv * 32 + i * 16 + q * 4;
            int ol = j * 16 + r;
            sm.outb[ml + 0][ol] = acc[i][j][0];
            sm.outb[ml + 1][ol] = acc[i][j][1];
            sm.outb[ml + 2][ol] = acc[i][j][2];
            sm.outb[ml + 3][ol] = acc[i][j][3];
        }
    __syncthreads();
    int b = m0 >> 12, h0 = (m0 >> 6) & 63;
    int w = tid & 63, sub = tid >> 6;
    #pragma unroll
    for (int oo = 0; oo < 16; ++oo) {
        int ol = oo * 4 + sub;
        #pragma unroll
        for (int hh = 0; hh < 2; ++hh) {
            unsafeAtomicAdd(
                &out[(((size_t)b * ON + o0 + ol) * HN + h0 + hh) * WN + w],
                sm.outb[hh * 64 + w][ol]);
        }
    }
}

extern "C" void kernel_launch(void* const* d_in, const int* in_sizes, int n_in,
                              void* d_out, int out_size, void* d_ws, size_t ws_size,
                              hipStream_t stream) {
    const float* x      = (const float*)d_in[0];
    const float* offset = (const float*)d_in[1];
    const float* mask   = (const float*)d_in[2];
    const float* weight = (const float*)d_in[3];
    float* out = (float*)d_out;

    // ws: xb fp32 16 MiB | wt bf16 1.125 MiB | A bf16 72 MiB  (~93.5 MB)
    float* xb = (float*)d_ws;
    short* wt = (short*)((char*)d_ws + 16777216);
    short* A  = (short*)((char*)d_ws + 16777216 + 1179648);

    hipLaunchKernelGGL(prep_kernel,   dim3(4352),   dim3(256), 0, stream,
                       x, weight, xb, wt, out);
    hipLaunchKernelGGL(sample_kernel, dim3(MN / 4), dim3(256), 0, stream,
                       xb, offset, mask, A);
    hipLaunchKernelGGL(gemm_kernel,   dim3(1024),   dim3(256), 0, stream,
                       A, wt, out);
}

// Round 5
// 179.815 us; speedup vs baseline: 1.0871x; 1.0871x over previous
//
#include <hip/hip_runtime.h>
#include <hip/hip_bf16.h>

// Problem: x(4,256,64,64), offset(4,18,64,64), mask(4,9,64,64),
// weight(256,256,3,3) -> out(4,256,64,64). stride=1, pad=1, K=3.
// R5: blocked fragment-ready layouts so ALL global_load_lds are contiguous
// (hypothesis: scattered-source glds caused the invariant 2.15e7 LDS
// conflict cycles). xb in bf16. No K-split, no atomics.
//   A'[mb 0..127][kc 0..287][row 0..127] of 16B chunks (8 bf16)
//   B'[ob 0..3]  [kc 0..287][row 0..63]  of 16B chunks
#define BN 4
#define CN 256
#define HN 64
#define WN 64
#define ON 256
#define KKN 9
#define HWN 4096
#define KDIM 2304   // 9*256
#define MN 16384    // B*H*W
#define KC 288      // KDIM/8 chunks

using frag_ab = __attribute__((ext_vector_type(8))) short;  // 8 bf16
using frag_cd = __attribute__((ext_vector_type(4))) float;  // 4 fp32

static __device__ inline short f2bf(float f) {
    union { float f; unsigned u; } v; v.f = f;
    unsigned r = v.u + 0x7fffu + ((v.u >> 16) & 1u);
    return (short)(r >> 16);
}
static __device__ inline float bf2f(short s) {
    union { unsigned u; float f; } v; v.u = ((unsigned)(unsigned short)s) << 16;
    return v.f;
}

static __device__ inline void async_copy16(const void* g, void* l) {
    __builtin_amdgcn_global_load_lds(
        (const __attribute__((address_space(1))) unsigned int*)g,
        (__attribute__((address_space(3))) unsigned int*)l,
        16, 0, 0);
}

// ---------- kernel 1: prep = transpose x -> BHWC bf16 | repack weight ------
// blocks [0,1024): x BCHW fp32 -> xb16 BHWC bf16
// blocks [1024,1312): weight (O,C,3,3) fp32 -> B'[ob][kc][row] bf16 chunks
__global__ __launch_bounds__(256) void prep_kernel(const float* __restrict__ x,
                                                   const float* __restrict__ wsrc,
                                                   short* __restrict__ xb16,
                                                   short* __restrict__ wtb) {
    int bidx = blockIdx.x;
    int tid  = threadIdx.x;
    if (bidx < 1024) {
        __shared__ float tile[64][65];
        int b   = bidx >> 8;
        int rem = bidx & 255;
        int c0  = (rem >> 6) * 64;
        int p0  = (rem & 63) * 64;
        int tp = tid & 63, tc = tid >> 6;
        for (int i = 0; i < 16; ++i) {
            int c = tc + i * 4;
            tile[c][tp] = x[(b * CN + c0 + c) * HWN + p0 + tp];
        }
        __syncthreads();
        int tcc = tid & 63, tpp = tid >> 6;
        for (int i = 0; i < 16; ++i) {
            int p = tpp + i * 4;
            xb16[(b * HWN + p0 + p) * CN + c0 + tcc] = f2bf(tile[tcc][p]);
        }
    } else {
        int chunk = (bidx - 1024) * 256 + tid;   // < 4*288*64 = 73728
        int ob  = chunk / (KC * 64);
        int rem = chunk - ob * (KC * 64);
        int kc  = rem >> 6;
        int row = rem & 63;
        int o   = ob * 64 + row;
        int kk  = kc >> 5;
        int oct = kc & 31;
        short8_impl: ;
        frag_ab v;
        #pragma unroll
        for (int e = 0; e < 8; ++e)
            v[e] = f2bf(wsrc[(o * CN + oct * 8 + e) * 9 + kk]);
        *(frag_ab*)&wtb[(size_t)chunk * 8] = v;
    }
}

// ---------- kernel 2: sample -> A'[mb][kc][row] bf16 chunks ----------
// grid 512: bid -> mb = bid>>2 (0..127), og = bid&3 (oct group of 8).
// thread: row = t&127 (m = mb*128+row), sub = t>>7 -> 4 octs each.
__global__ __launch_bounds__(256) void sample_kernel(const short* __restrict__ xb16,
                                                     const float* __restrict__ offs,
                                                     const float* __restrict__ maskp,
                                                     short* __restrict__ A) {
    int t   = threadIdx.x;
    int mb  = blockIdx.x >> 2;
    int og  = blockIdx.x & 3;
    int row = t & 127;
    int sub = t >> 7;
    int m = mb * 128 + row;
    int b = m >> 12;
    int h = (m >> 6) & 63;
    int w = m & 63;
    int oct0 = og * 8 + sub * 4;

    #pragma unroll
    for (int kk = 0; kk < KKN; ++kk) {
        int ki = kk / 3, kj = kk - ki * 3;
        int obase = ((b * 18 + kk * 2) * 64 + h) * 64 + w;
        float dy = offs[obase];
        float dx = offs[obase + HWN];
        float mv = maskp[((b * 9 + kk) * 64 + h) * 64 + w];
        float py = (float)(h - 1 + ki) + dy;
        float px = (float)(w - 1 + kj) + dx;
        float y0f = floorf(py), x0f = floorf(px);
        float wy = py - y0f, wx = px - x0f;
        int y0 = (int)y0f, x0 = (int)x0f;
        const short* rp[4];
        float cw[4];
        #pragma unroll
        for (int cy = 0; cy < 2; ++cy)
            #pragma unroll
            for (int cx = 0; cx < 2; ++cx) {
                int yy = y0 + cy, xx = x0 + cx;
                bool valid = (yy >= 0 && yy < HN && xx >= 0 && xx < WN);
                int yc = min(max(yy, 0), HN - 1);
                int xc = min(max(xx, 0), WN - 1);
                rp[cy * 2 + cx] = xb16 + (size_t)(((b * HN + yc) * WN + xc)) * CN;
                float wgt = (cy ? wy : 1.f - wy) * (cx ? wx : 1.f - wx) * mv;
                cw[cy * 2 + cx] = valid ? wgt : 0.f;
            }
        #pragma unroll
        for (int oc = 0; oc < 4; ++oc) {
            int oct = oct0 + oc;
            frag_ab v0 = *(const frag_ab*)(rp[0] + oct * 8);
            frag_ab v1 = *(const frag_ab*)(rp[1] + oct * 8);
            frag_ab v2 = *(const frag_ab*)(rp[2] + oct * 8);
            frag_ab v3 = *(const frag_ab*)(rp[3] + oct * 8);
            frag_ab res;
            #pragma unroll
            for (int e = 0; e < 8; e += 2) {
                float a0 = cw[0] * bf2f(v0[e]) + cw[1] * bf2f(v1[e])
                         + cw[2] * bf2f(v2[e]) + cw[3] * bf2f(v3[e]);
                float a1 = cw[0] * bf2f(v0[e + 1]) + cw[1] * bf2f(v1[e + 1])
                         + cw[2] * bf2f(v2[e + 1]) + cw[3] * bf2f(v3[e + 1]);
                __hip_bfloat162 p2 = __float22bfloat162_rn(make_float2(a0, a1));
                res[e]     = *(short*)&p2.x;
                res[e + 1] = *(short*)&p2.y;
            }
            int kc = kk * 32 + oct;
            *(frag_ab*)&A[(((size_t)mb * KC + kc) * 128 + row) * 8] = res;
        }
    }
}

// ---------- kernel 3: GEMM  MT=128, NT=64, BK=128, full K, grid 512 --------
// Stage per iter: A 32KB + B 16KB, both CONTIGUOUS (global and LDS linear).
// LDS chunk (kcl*Rows + row); frag read addr = ((s*4+q)*Rows + frow)*16:
// per 16-lane phase r is contiguous 256B -> 2-way bank aliasing = free.
#define MT 128
#define NT 64
#define BK 128
#define NITER 18   // KDIM/BK

__global__ __launch_bounds__(256, 2) void gemm_kernel(const short* __restrict__ A,
                                                      const short* __restrict__ wtb,
                                                      float* __restrict__ out) {
    __shared__ union {
        struct { short A[2048 * 8]; short B[1024 * 8]; } st;  // 32KB + 16KB
        float outb[MT][65];                                    // 33.3 KB
    } sm;
    int tid  = threadIdx.x;
    int bid  = blockIdx.x;
    int mblk = bid & 127;           // 8 blocks sharing A-tile -> same XCD
    int oblk = bid >> 7;
    int m0 = mblk * MT, o0 = oblk * NT;
    int wv = tid >> 6, lane = tid & 63;
    int q = lane >> 4, r = lane & 15;

    frag_cd acc[2][4];
    #pragma unroll
    for (int i = 0; i < 2; ++i)
        #pragma unroll
        for (int j = 0; j < 4; ++j)
            acc[i][j] = (frag_cd){0.f, 0.f, 0.f, 0.f};

    const short* Abase = A   + ((size_t)mblk * KC) * 128 * 8;
    const short* Bbase = wtb + ((size_t)oblk * KC) * 64 * 8;

    for (int it = 0; it < NITER; ++it) {
        __syncthreads();
        // A: 2048 chunks contiguous; 8 rounds x 256 threads
        const short* ga = Abase + (size_t)(it * 16) * 128 * 8 + tid * 8;
        short* la = sm.st.A + tid * 8;
        #pragma unroll
        for (int r8 = 0; r8 < 8; ++r8)
            async_copy16(ga + r8 * 2048, la + r8 * 2048);
        // B: 1024 chunks contiguous; 4 rounds
        const short* gb = Bbase + (size_t)(it * 16) * 64 * 8 + tid * 8;
        short* lb = sm.st.B + tid * 8;
        #pragma unroll
        for (int r4 = 0; r4 < 4; ++r4)
            async_copy16(gb + r4 * 2048, lb + r4 * 2048);
        __syncthreads();
        #pragma unroll
        for (int s = 0; s < 4; ++s) {
            frag_ab af[2], bf[4];
            #pragma unroll
            for (int i = 0; i < 2; ++i)
                af[i] = *(const frag_ab*)
                    &sm.st.A[(((s * 4 + q) * 128) + wv * 32 + i * 16 + r) * 8];
            #pragma unroll
            for (int j = 0; j < 4; ++j)
                bf[j] = *(const frag_ab*)
                    &sm.st.B[(((s * 4 + q) * 64) + j * 16 + r) * 8];
            #pragma unroll
            for (int i = 0; i < 2; ++i)
                #pragma unroll
                for (int j = 0; j < 4; ++j)
                    acc[i][j] = __builtin_amdgcn_mfma_f32_16x16x32_bf16(
                        af[i], bf[j], acc[i][j], 0, 0, 0);
        }
    }
    __syncthreads();
    // epilogue: C-frag (row = q*4+reg, col = r) -> LDS -> coalesced BOHW
    #pragma unroll
    for (int i = 0; i < 2; ++i)
        #pragma unroll
        for (int j = 0; j < 4; ++j) {
            int ml = wv * 32 + i * 16 + q * 4;
            int ol = j * 16 + r;
            sm.outb[ml + 0][ol] = acc[i][j][0];
            sm.outb[ml + 1][ol] = acc[i][j][1];
            sm.outb[ml + 2][ol] = acc[i][j][2];
            sm.outb[ml + 3][ol] = acc[i][j][3];
        }
    __syncthreads();
    int b = m0 >> 12, h0 = (m0 >> 6) & 63;
    int w = tid & 63, sub = tid >> 6;
    #pragma unroll
    for (int oo = 0; oo < 16; ++oo) {
        int ol = oo * 4 + sub;
        #pragma unroll
        for (int hh = 0; hh < 2; ++hh) {
            out[(((size_t)b * ON + o0 + ol) * HN + h0 + hh) * WN + w] =
                sm.outb[hh * 64 + w][ol];
        }
    }
}

extern "C" void kernel_launch(void* const* d_in, const int* in_sizes, int n_in,
                              void* d_out, int out_size, void* d_ws, size_t ws_size,
                              hipStream_t stream) {
    const float* x      = (const float*)d_in[0];
    const float* offset = (const float*)d_in[1];
    const float* mask   = (const float*)d_in[2];
    const float* weight = (const float*)d_in[3];
    float* out = (float*)d_out;

    // ws: xb16 bf16 8 MiB | wtb bf16 1.125 MiB | A' bf16 72 MiB
    short* xb16 = (short*)d_ws;
    short* wtb  = (short*)((char*)d_ws + 8388608);
    short* A    = (short*)((char*)d_ws + 8388608 + 1179648);

    hipLaunchKernelGGL(prep_kernel,   dim3(1312), dim3(256), 0, stream,
                       x, weight, xb16, wtb);
    hipLaunchKernelGGL(sample_kernel, dim3(512),  dim3(256), 0, stream,
                       xb16, offset, mask, A);
    hipLaunchKernelGGL(gemm_kernel,   dim3(512),  dim3(256), 0, stream,
                       A, wtb, out);
}

// Round 6
// 155.286 us; speedup vs baseline: 1.2589x; 1.1580x over previous
//
#include <hip/hip_runtime.h>
#include <hip/hip_bf16.h>

// Problem: x(4,256,64,64), offset(4,18,64,64), mask(4,9,64,64),
// weight(256,256,3,3) -> out(4,256,64,64). stride=1, pad=1, K=3.
// R6: LDS-free GEMM. A'/B' are fragment-ready blocked layouts, so MFMA
// fragments load directly global->VGPR (coalesced dwordx4); no barriers,
// 3-buffer register pipeline (prefetch distance 2 K-steps). R5 post-mortem:
// glds DMA writes cost ~48 LDS-port cycles each (counter invariant across
// source patterns) -> staging through LDS was the bottleneck.
//   A'[mb 0..127][kc 0..287][row 0..127] of 16B chunks (8 bf16)
//   B'[ob 0..3]  [kc 0..287][row 0..63]  of 16B chunks
#define BN 4
#define CN 256
#define HN 64
#define WN 64
#define ON 256
#define KKN 9
#define HWN 4096
#define KDIM 2304   // 9*256
#define MN 16384    // B*H*W
#define KC 288      // KDIM/8 chunks

using frag_ab = __attribute__((ext_vector_type(8))) short;  // 8 bf16
using frag_cd = __attribute__((ext_vector_type(4))) float;  // 4 fp32

static __device__ inline short f2bf(float f) {
    union { float f; unsigned u; } v; v.f = f;
    unsigned r = v.u + 0x7fffu + ((v.u >> 16) & 1u);
    return (short)(r >> 16);
}
static __device__ inline float bf2f(short s) {
    union { unsigned u; float f; } v; v.u = ((unsigned)(unsigned short)s) << 16;
    return v.f;
}

// ---------- kernel 1: prep = transpose x -> BHWC bf16 | repack weight ------
__global__ __launch_bounds__(256) void prep_kernel(const float* __restrict__ x,
                                                   const float* __restrict__ wsrc,
                                                   short* __restrict__ xb16,
                                                   short* __restrict__ wtb) {
    int bidx = blockIdx.x;
    int tid  = threadIdx.x;
    if (bidx < 1024) {
        __shared__ float tile[64][65];
        int b   = bidx >> 8;
        int rem = bidx & 255;
        int c0  = (rem >> 6) * 64;
        int p0  = (rem & 63) * 64;
        int tp = tid & 63, tc = tid >> 6;
        for (int i = 0; i < 16; ++i) {
            int c = tc + i * 4;
            tile[c][tp] = x[(b * CN + c0 + c) * HWN + p0 + tp];
        }
        __syncthreads();
        int tcc = tid & 63, tpp = tid >> 6;
        for (int i = 0; i < 16; ++i) {
            int p = tpp + i * 4;
            xb16[(b * HWN + p0 + p) * CN + c0 + tcc] = f2bf(tile[tcc][p]);
        }
    } else {
        int chunk = (bidx - 1024) * 256 + tid;   // < 4*288*64 = 73728
        int ob  = chunk / (KC * 64);
        int rem = chunk - ob * (KC * 64);
        int kc  = rem >> 6;
        int row = rem & 63;
        int o   = ob * 64 + row;
        int kk  = kc >> 5;
        int oct = kc & 31;
        frag_ab v;
        #pragma unroll
        for (int e = 0; e < 8; ++e)
            v[e] = f2bf(wsrc[(o * CN + oct * 8 + e) * 9 + kk]);
        *(frag_ab*)&wtb[(size_t)chunk * 8] = v;
    }
}

// ---------- kernel 2: sample -> A'[mb][kc][row] bf16 chunks ----------
__global__ __launch_bounds__(256) void sample_kernel(const short* __restrict__ xb16,
                                                     const float* __restrict__ offs,
                                                     const float* __restrict__ maskp,
                                                     short* __restrict__ A) {
    int t   = threadIdx.x;
    int mb  = blockIdx.x >> 2;
    int og  = blockIdx.x & 3;
    int row = t & 127;
    int sub = t >> 7;
    int m = mb * 128 + row;
    int b = m >> 12;
    int h = (m >> 6) & 63;
    int w = m & 63;
    int oct0 = og * 8 + sub * 4;

    #pragma unroll
    for (int kk = 0; kk < KKN; ++kk) {
        int ki = kk / 3, kj = kk - ki * 3;
        int obase = ((b * 18 + kk * 2) * 64 + h) * 64 + w;
        float dy = offs[obase];
        float dx = offs[obase + HWN];
        float mv = maskp[((b * 9 + kk) * 64 + h) * 64 + w];
        float py = (float)(h - 1 + ki) + dy;
        float px = (float)(w - 1 + kj) + dx;
        float y0f = floorf(py), x0f = floorf(px);
        float wy = py - y0f, wx = px - x0f;
        int y0 = (int)y0f, x0 = (int)x0f;
        const short* rp[4];
        float cw[4];
        #pragma unroll
        for (int cy = 0; cy < 2; ++cy)
            #pragma unroll
            for (int cx = 0; cx < 2; ++cx) {
                int yy = y0 + cy, xx = x0 + cx;
                bool valid = (yy >= 0 && yy < HN && xx >= 0 && xx < WN);
                int yc = min(max(yy, 0), HN - 1);
                int xc = min(max(xx, 0), WN - 1);
                rp[cy * 2 + cx] = xb16 + (size_t)(((b * HN + yc) * WN + xc)) * CN;
                float wgt = (cy ? wy : 1.f - wy) * (cx ? wx : 1.f - wx) * mv;
                cw[cy * 2 + cx] = valid ? wgt : 0.f;
            }
        #pragma unroll
        for (int oc = 0; oc < 4; ++oc) {
            int oct = oct0 + oc;
            frag_ab v0 = *(const frag_ab*)(rp[0] + oct * 8);
            frag_ab v1 = *(const frag_ab*)(rp[1] + oct * 8);
            frag_ab v2 = *(const frag_ab*)(rp[2] + oct * 8);
            frag_ab v3 = *(const frag_ab*)(rp[3] + oct * 8);
            frag_ab res;
            #pragma unroll
            for (int e = 0; e < 8; e += 2) {
                float a0 = cw[0] * bf2f(v0[e]) + cw[1] * bf2f(v1[e])
                         + cw[2] * bf2f(v2[e]) + cw[3] * bf2f(v3[e]);
                float a1 = cw[0] * bf2f(v0[e + 1]) + cw[1] * bf2f(v1[e + 1])
                         + cw[2] * bf2f(v2[e + 1]) + cw[3] * bf2f(v3[e + 1]);
                __hip_bfloat162 p2 = __float22bfloat162_rn(make_float2(a0, a1));
                res[e]     = *(short*)&p2.x;
                res[e + 1] = *(short*)&p2.y;
            }
            int kc = kk * 32 + oct;
            *(frag_ab*)&A[(((size_t)mb * KC + kc) * 128 + row) * 8] = res;
        }
    }
}

// ---------- kernel 3: LDS-free GEMM. MT=128, NT=64, grid 512 ----------
// K-step ks (=32 k): af(i) at A' chunk (ks*4+q)*128 + wv*32+i*16+r;
// bf(j) at B' chunk (ks*4+q)*64 + j*16+r. 72 steps, 3-buffer rotation.
#define MT 128
#define NT 64

__global__ __launch_bounds__(256, 2) void gemm_kernel(const short* __restrict__ A,
                                                      const short* __restrict__ wtb,
                                                      float* __restrict__ out) {
    __shared__ float outb[MT][65];   // epilogue transpose only
    int tid  = threadIdx.x;
    int bid  = blockIdx.x;
    int mblk = bid & 127;            // A-tile sharers land on one XCD
    int oblk = bid >> 7;
    int m0 = mblk * MT, o0 = oblk * NT;
    int wv = tid >> 6, lane = tid & 63;
    int q = lane >> 4, r = lane & 15;

    frag_cd acc[2][4];
    #pragma unroll
    for (int i = 0; i < 2; ++i)
        #pragma unroll
        for (int j = 0; j < 4; ++j)
            acc[i][j] = (frag_cd){0.f, 0.f, 0.f, 0.f};

    // lane-fixed bases (short units). ks strides: A 4096, B 2048. i/j: 128.
    const short* ap = A   + ((size_t)mblk * KC + q) * 1024 + (wv * 32 + r) * 8;
    const short* bp = wtb + ((size_t)oblk * KC + q) * 512 + r * 8;

    frag_ab af0[2], af1[2], af2[2], bf0[4], bf1[4], bf2[4];

#define LOADK(AF, BF, ks)                                                  \
    {                                                                      \
        const short* a_ = ap + (size_t)(ks) * 4096;                        \
        AF[0] = *(const frag_ab*)(a_);                                     \
        AF[1] = *(const frag_ab*)(a_ + 128);                               \
        const short* b_ = bp + (size_t)(ks) * 2048;                        \
        BF[0] = *(const frag_ab*)(b_);                                     \
        BF[1] = *(const frag_ab*)(b_ + 128);                               \
        BF[2] = *(const frag_ab*)(b_ + 256);                               \
        BF[3] = *(const frag_ab*)(b_ + 384);                               \
    }

#define MFMAK(AF, BF)                                                      \
    {                                                                      \
        _Pragma("unroll")                                                  \
        for (int i = 0; i < 2; ++i) {                                      \
            _Pragma("unroll")                                              \
            for (int j = 0; j < 4; ++j)                                    \
                acc[i][j] = __builtin_amdgcn_mfma_f32_16x16x32_bf16(       \
                    AF[i], BF[j], acc[i][j], 0, 0, 0);                     \
        }                                                                  \
    }

    LOADK(af0, bf0, 0)
    LOADK(af1, bf1, 1)
    for (int kt = 0; kt < 23; ++kt) {
        int ks = kt * 3;
        LOADK(af2, bf2, ks + 2)
        MFMAK(af0, bf0)
        LOADK(af0, bf0, ks + 3)
        MFMAK(af1, bf1)
        LOADK(af1, bf1, ks + 4)
        MFMAK(af2, bf2)
    }
    // peel ks = 69,70,71 (69,70 already loaded; load 71)
    LOADK(af2, bf2, 71)
    MFMAK(af0, bf0)
    MFMAK(af1, bf1)
    MFMAK(af2, bf2)

    // ---- epilogue: C-frag (row = q*4+reg, col = r) -> LDS -> BOHW ----
    #pragma unroll
    for (int i = 0; i < 2; ++i)
        #pragma unroll
        for (int j = 0; j < 4; ++j) {
            int ml = wv * 32 + i * 16 + q * 4;
            int ol = j * 16 + r;
            outb[ml + 0][ol] = acc[i][j][0];
            outb[ml + 1][ol] = acc[i][j][1];
            outb[ml + 2][ol] = acc[i][j][2];
            outb[ml + 3][ol] = acc[i][j][3];
        }
    __syncthreads();
    int b = m0 >> 12, h0 = (m0 >> 6) & 63;
    int w = tid & 63, sub = tid >> 6;
    #pragma unroll
    for (int oo = 0; oo < 16; ++oo) {
        int ol = oo * 4 + sub;
        #pragma unroll
        for (int hh = 0; hh < 2; ++hh) {
            out[(((size_t)b * ON + o0 + ol) * HN + h0 + hh) * WN + w] =
                outb[hh * 64 + w][ol];
        }
    }
}

extern "C" void kernel_launch(void* const* d_in, const int* in_sizes, int n_in,
                              void* d_out, int out_size, void* d_ws, size_t ws_size,
                              hipStream_t stream) {
    const float* x      = (const float*)d_in[0];
    const float* offset = (const float*)d_in[1];
    const float* mask   = (const float*)d_in[2];
    const float* weight = (const float*)d_in[3];
    float* out = (float*)d_out;

    // ws: xb16 bf16 8 MiB | wtb bf16 1.125 MiB | A' bf16 72 MiB
    short* xb16 = (short*)d_ws;
    short* wtb  = (short*)((char*)d_ws + 8388608);
    short* A    = (short*)((char*)d_ws + 8388608 + 1179648);

    hipLaunchKernelGGL(prep_kernel,   dim3(1312), dim3(256), 0, stream,
                       x, weight, xb16, wtb);
    hipLaunchKernelGGL(sample_kernel, dim3(512),  dim3(256), 0, stream,
                       xb16, offset, mask, A);
    hipLaunchKernelGGL(gemm_kernel,   dim3(512),  dim3(256), 0, stream,
                       A, wtb, out);
}